// Round 4
// baseline (346.946 us; speedup 1.0000x reference)
//
#include <hip/hip_runtime.h>
#include <hip/hip_bf16.h>

// Problem constants (from reference setup_inputs)
#define C1    256      // feature channels
#define C2    128      // encoder channels
#define COUT  256      // output channels
#define KTOT  384      // C1 + C2
#define MM    4096     // feature length
#define NN    16384    // encoder / output length
#define BB    8        // batch
#define BN_EPS 1e-5f
#define SLOPE 0.2f

typedef float  f32x4  __attribute__((ext_vector_type(4)));
typedef __bf16 bf16x8 __attribute__((ext_vector_type(8)));
typedef unsigned short u16x8 __attribute__((ext_vector_type(8)));
typedef unsigned short u16x4 __attribute__((ext_vector_type(4)));

#define GLOBAL_AS __attribute__((address_space(1)))
#define LDS_AS    __attribute__((address_space(3)))

static __device__ __forceinline__ unsigned short f2bf(float f) {
    // round-to-nearest-even f32 -> bf16 bits (inputs are finite)
    unsigned int u = __builtin_bit_cast(unsigned int, f);
    unsigned int r = (u + 0x7FFFu + ((u >> 16) & 1u)) >> 16;
    return (unsigned short)r;
}

static __device__ __forceinline__ float bf2f(unsigned short b) {
    return __builtin_bit_cast(float, (unsigned int)b << 16);
}

static __device__ __forceinline__ bf16x8 ld_frag_g(const unsigned short* p) {
    union { u16x8 s; bf16x8 b; } cvt;
    cvt.s = *reinterpret_cast<const u16x8*>(p);
    return cvt.b;
}

// ---------------------------------------------------------------------------
// K0: transpose + convert  in[R][C] f32 (per batch)  ->  out[C][R] bf16
// 64x64 tiles; coalesced f32 reads, coalesced bf16 writes.
// ---------------------------------------------------------------------------
__global__ __launch_bounds__(256) void k0_transpose(const float* __restrict__ in,
                                                    unsigned short* __restrict__ out,
                                                    int R, int C) {
    __shared__ float f[64][68];
    const int c0 = blockIdx.x * 64, r0 = blockIdx.y * 64;
    const float* inb = in + (size_t)blockIdx.z * R * C;
    unsigned short* outb = out + (size_t)blockIdx.z * R * C;
    const int t = threadIdx.x;
#pragma unroll
    for (int q = 0; q < 4; q++) {
        int idx = q * 256 + t;
        int ri = idx >> 4, c4 = (idx & 15) * 4;
        float4 v = *reinterpret_cast<const float4*>(&inb[(size_t)(r0 + ri) * C + c0 + c4]);
        *reinterpret_cast<float4*>(&f[ri][c4]) = v;
    }
    __syncthreads();
#pragma unroll
    for (int q = 0; q < 4; q++) {
        int idx = q * 256 + t;
        int oc = idx >> 4, rq = (idx & 15) * 4;
        u16x4 u;
#pragma unroll
        for (int j = 0; j < 4; j++) u[j] = f2bf(f[rq + j][oc]);
        *reinterpret_cast<u16x4*>(&outb[(size_t)(c0 + oc) * R + r0 + rq]) = u;
    }
}

// ---------------------------------------------------------------------------
// K1: ZtB[b][m][o] = bf16( sum_c featT[b][m][c] * Wt[o][C2+c] )
// pure-register MFMA GEMM: no LDS, no barriers. tile 64m x 64o per block.
// ---------------------------------------------------------------------------
__global__ __launch_bounds__(256, 4) void k1_zt(const unsigned short* __restrict__ featT,
                                                const unsigned short* __restrict__ Wt,
                                                unsigned short* __restrict__ ZtB) {
    const int mb = blockIdx.x * 64, ob = blockIdx.y * 64, b = blockIdx.z;
    const int tid = threadIdx.x;
    const int wid = tid >> 6, lane = tid & 63;
    const int r = lane & 15, g = lane >> 4;
    const int wm = (wid >> 1) * 32, wo = (wid & 1) * 32;

    f32x4 acc[2][2];
#pragma unroll
    for (int i = 0; i < 2; i++)
#pragma unroll
        for (int j = 0; j < 2; j++) acc[i][j] = (f32x4){0.f, 0.f, 0.f, 0.f};

    const unsigned short* fA = featT + (size_t)(b * MM + mb) * C1;

#pragma unroll
    for (int kp = 0; kp < 2; kp++)
#pragma unroll
        for (int ks = 0; ks < 4; ks++) {
            const int kb = kp * 128 + ks * 32 + g * 8;
            bf16x8 a0 = ld_frag_g(&fA[(size_t)(wm +  0 + r) * C1 + kb]);
            bf16x8 a1 = ld_frag_g(&fA[(size_t)(wm + 16 + r) * C1 + kb]);
            bf16x8 b0 = ld_frag_g(&Wt[(size_t)(ob + wo +  0 + r) * KTOT + C2 + kb]);
            bf16x8 b1 = ld_frag_g(&Wt[(size_t)(ob + wo + 16 + r) * KTOT + C2 + kb]);
            acc[0][0] = __builtin_amdgcn_mfma_f32_16x16x32_bf16(a0, b0, acc[0][0], 0, 0, 0);
            acc[0][1] = __builtin_amdgcn_mfma_f32_16x16x32_bf16(a0, b1, acc[0][1], 0, 0, 0);
            acc[1][0] = __builtin_amdgcn_mfma_f32_16x16x32_bf16(a1, b0, acc[1][0], 0, 0, 0);
            acc[1][1] = __builtin_amdgcn_mfma_f32_16x16x32_bf16(a1, b1, acc[1][1], 0, 0, 0);
        }

    // D layout: row = 4*g + i, col = r
#pragma unroll
    for (int fm = 0; fm < 2; fm++)
#pragma unroll
        for (int fo = 0; fo < 2; fo++)
#pragma unroll
            for (int i = 0; i < 4; i++) {
                int m = mb + wm + fm * 16 + g * 4 + i;
                int o = ob + wo + fo * 16 + r;
                ZtB[(size_t)(b * MM + m) * COUT + o] = f2bf(acc[fm][fo][i]);
            }
}

// ---------------------------------------------------------------------------
// K2: y[b][o][n] = bias[o] + ZtB[b][idx[b,n]][o] + sum_k encT[b][n][k]*Wt[o][k]
// tile 64o x 128n. All MFMA frags loaded directly from global (bf16, L2/L3-hot).
// Zt gather DMA'd into 16KB swizzled LDS, issued FIRST for max overlap.
// ---------------------------------------------------------------------------
__global__ __launch_bounds__(256, 4) void k2_main(const unsigned short* __restrict__ encT,
                                                  const unsigned short* __restrict__ Wt,
                                                  const float* __restrict__ bias,
                                                  const int*   __restrict__ idx,
                                                  const unsigned short* __restrict__ ZtB,
                                                  float* __restrict__ y,
                                                  float* __restrict__ sums,    // [BB][COUT]
                                                  float* __restrict__ sumsq) { // [BB][COUT]
    const int nb = blockIdx.x * 128, ob = blockIdx.y * 64, b = blockIdx.z;
    const int tid = threadIdx.x;

    __shared__ unsigned short ZlB[128 * 64];  // gathered Zt rows, bf16, 16 KB
    __shared__ float lsum[64], lsq[64];
    if (tid < 64) { lsum[tid] = 0.f; lsq[tid] = 0.f; }

    const int wid = tid >> 6, lane = tid & 63;
    const int r = lane & 15, g = lane >> 4;
    const int wo = (wid >> 1) * 32;  // wave's o offset (0/32)
    const int wn = (wid & 1) * 64;   // wave's n offset (0/64)

    // ---- issue gather DMA first (linear LDS dest, XOR-swizzled global src) --
    {
        const int* idxb = idx + b * NN + nb;
        const int lrow = lane >> 3, lcol = lane & 7;   // 8 rows / gld_lds
#pragma unroll
        for (int it = 0; it < 4; it++) {
            const int wrow = wid * 32 + it * 8;
            const int row  = wrow + lrow;
            const int zi   = idxb[row];
            const unsigned short* src = &ZtB[(size_t)(b * MM + zi) * COUT + ob +
                                             ((lcol ^ (row & 7)) << 3)];
            __builtin_amdgcn_global_load_lds(
                (const GLOBAL_AS unsigned int*)src,
                (LDS_AS unsigned int*)(&ZlB[wrow * 64]), 16, 0, 0);
        }
    }

    // ---- W fragments (L2-resident) ----
    bf16x8 wf[4][2];
#pragma unroll
    for (int ks = 0; ks < 4; ks++)
#pragma unroll
        for (int fr = 0; fr < 2; fr++)
            wf[ks][fr] = ld_frag_g(&Wt[(size_t)(ob + wo + fr * 16 + r) * KTOT +
                                       ks * 32 + g * 8]);

    // ---- enc fragments direct from encT + MFMA ----
    f32x4 acc[2][4];
#pragma unroll
    for (int i = 0; i < 2; i++)
#pragma unroll
        for (int j = 0; j < 4; j++) acc[i][j] = (f32x4){0.f, 0.f, 0.f, 0.f};

    const unsigned short* eB = encT + (size_t)(b * NN + nb) * C2;
#pragma unroll
    for (int ks = 0; ks < 4; ks++) {
        const int kb = ks * 32 + g * 8;
        bf16x8 bfr[4];
#pragma unroll
        for (int fn = 0; fn < 4; fn++)
            bfr[fn] = ld_frag_g(&eB[(size_t)(wn + fn * 16 + r) * C2 + kb]);
#pragma unroll
        for (int fn = 0; fn < 4; fn++) {
            acc[0][fn] = __builtin_amdgcn_mfma_f32_16x16x32_bf16(wf[ks][0], bfr[fn], acc[0][fn], 0, 0, 0);
            acc[1][fn] = __builtin_amdgcn_mfma_f32_16x16x32_bf16(wf[ks][1], bfr[fn], acc[1][fn], 0, 0, 0);
        }
    }

    __syncthreads();  // drains gather DMA (vmcnt(0) before barrier) + lsum init

    float bi[2][4];
#pragma unroll
    for (int fo = 0; fo < 2; fo++)
#pragma unroll
        for (int i = 0; i < 4; i++)
            bi[fo][i] = bias[ob + wo + fo * 16 + g * 4 + i];

    float s_[2][4] = {{0.f,0.f,0.f,0.f},{0.f,0.f,0.f,0.f}};
    float q_[2][4] = {{0.f,0.f,0.f,0.f},{0.f,0.f,0.f,0.f}};
#pragma unroll
    for (int fo = 0; fo < 2; fo++)
#pragma unroll
        for (int fn = 0; fn < 4; fn++) {
            const int n_loc = wn + fn * 16 + r;
            const int obase = wo + fo * 16 + g * 4;
            const int pg = (obase >> 3) ^ (n_loc & 7);   // swizzled granule
            const int h  = (obase >> 2) & 1;
            const u16x4 z = *reinterpret_cast<const u16x4*>(
                &ZlB[n_loc * 64 + (pg << 3) + (h << 2)]);
#pragma unroll
            for (int i = 0; i < 4; i++) {
                int o_loc = obase + i;
                float v = acc[fo][fn][i] + bf2f(z[i]) + bi[fo][i];
                y[(size_t)(b * COUT + ob + o_loc) * NN + nb + n_loc] = v;
                s_[fo][i] += v;
                q_[fo][i] += v * v;
            }
        }

    // reduce across the 16 col-lanes (o_loc constant under xor of low 4 bits)
#pragma unroll
    for (int d = 1; d < 16; d <<= 1)
#pragma unroll
        for (int fo = 0; fo < 2; fo++)
#pragma unroll
            for (int i = 0; i < 4; i++) {
                s_[fo][i] += __shfl_xor(s_[fo][i], d);
                q_[fo][i] += __shfl_xor(q_[fo][i], d);
            }
    if (r == 0) {
#pragma unroll
        for (int fo = 0; fo < 2; fo++)
#pragma unroll
            for (int i = 0; i < 4; i++) {
                int o_loc = wo + fo * 16 + g * 4 + i;
                atomicAdd(&lsum[o_loc], s_[fo][i]);
                atomicAdd(&lsq[o_loc],  q_[fo][i]);
            }
    }
    __syncthreads();
    if (tid < 64) {
        atomicAdd(&sums [b * COUT + ob + tid], lsum[tid]);
        atomicAdd(&sumsq[b * COUT + ob + tid], lsq[tid]);
    }
}

// ---------------------------------------------------------------------------
// K3: fold per-(b,o) partial sums into per-channel affine a,c
// ---------------------------------------------------------------------------
__global__ void k3_stats(const float* __restrict__ sums,
                         const float* __restrict__ sumsq,
                         const float* __restrict__ gamma,
                         const float* __restrict__ beta,
                         float* __restrict__ ac) {  // [0..255]=a, [256..511]=c
    const int o = threadIdx.x;
    float s = 0.f, q = 0.f;
#pragma unroll
    for (int b = 0; b < BB; b++) {
        s += sums [b * COUT + o];
        q += sumsq[b * COUT + o];
    }
    const float inv_cnt = 1.0f / ((float)BB * (float)NN);
    float mean = s * inv_cnt;
    float var  = q * inv_cnt - mean * mean;
    float a = gamma[o] * rsqrtf(var + BN_EPS);
    float c = beta[o] - mean * a;
    ac[o] = a;
    ac[COUT + o] = c;
}

// ---------------------------------------------------------------------------
// K4: in-place normalize + LeakyReLU, float4 grid-stride
// ---------------------------------------------------------------------------
__global__ __launch_bounds__(256) void k4_norm(float* __restrict__ y,
                                               const float* __restrict__ ac) {
    const size_t total4 = (size_t)BB * COUT * NN / 4;
    const size_t stride = (size_t)gridDim.x * 256;
    for (size_t i = (size_t)blockIdx.x * 256 + threadIdx.x; i < total4; i += stride) {
        float4 v = reinterpret_cast<float4*>(y)[i];
        int o = (int)((i * 4) >> 14) & 255;  // (elem / NN) % COUT, NN = 2^14
        float a = ac[o], c = ac[COUT + o];
        float t0 = a * v.x + c; v.x = t0 > 0.f ? t0 : SLOPE * t0;
        float t1 = a * v.y + c; v.y = t1 > 0.f ? t1 : SLOPE * t1;
        float t2 = a * v.z + c; v.z = t2 > 0.f ? t2 : SLOPE * t2;
        float t3 = a * v.w + c; v.w = t3 > 0.f ? t3 : SLOPE * t3;
        reinterpret_cast<float4*>(y)[i] = v;
    }
}

extern "C" void kernel_launch(void* const* d_in, const int* in_sizes, int n_in,
                              void* d_out, int out_size, void* d_ws, size_t ws_size,
                              hipStream_t stream) {
    const float* feature = (const float*)d_in[0];   // [8,256,4096]
    const float* enc     = (const float*)d_in[1];   // [8,128,16384]
    const int*   idx     = (const int*)  d_in[2];   // [8,16384]
    const float* W       = (const float*)d_in[3];   // [384,256]
    const float* bias    = (const float*)d_in[4];   // [256]
    const float* gamma   = (const float*)d_in[5];   // [256]
    const float* beta    = (const float*)d_in[6];   // [256]
    float* out = (float*)d_out;                     // [8,256,16384]

    // workspace layout (bytes, all 16B-aligned)
    float* sums  = (float*)d_ws;                         // 8 KB
    float* sumsq = sums + BB * COUT;                     // 8 KB
    float* ac    = sumsq + BB * COUT;                    // 2 KB
    unsigned short* ZtB   = (unsigned short*)(ac + 2 * COUT);      // 16 MiB
    unsigned short* featT = ZtB   + (size_t)BB * MM * COUT;        // 16 MiB
    unsigned short* encT  = featT + (size_t)BB * MM * C1;          // 32 MiB
    unsigned short* Wt    = encT  + (size_t)BB * NN * C2;          // 192 KB

    hipMemsetAsync(sums, 0, 2 * BB * COUT * sizeof(float), stream);

    // prep: transpose+convert to bf16
    k0_transpose<<<dim3(MM / 64, C1 / 64, BB),   256, 0, stream>>>(feature, featT, C1, MM);
    k0_transpose<<<dim3(NN / 64, C2 / 64, BB),   256, 0, stream>>>(enc, encT, C2, NN);
    k0_transpose<<<dim3(COUT / 64, KTOT / 64, 1),256, 0, stream>>>(W, Wt, KTOT, COUT);

    k1_zt  <<<dim3(MM / 64, COUT / 64, BB), 256, 0, stream>>>(featT, Wt, ZtB);
    k2_main<<<dim3(NN / 128, COUT / 64, BB), 256, 0, stream>>>(encT, Wt, bias, idx, ZtB,
                                                               out, sums, sumsq);
    k3_stats<<<1, COUT, 0, stream>>>(sums, sumsq, gamma, beta, ac);
    k4_norm<<<2048, 256, 0, stream>>>(out, ac);
}